// Round 6
// baseline (970.341 us; speedup 1.0000x reference)
//
#include <hip/hip_runtime.h>
#include <hip/hip_bf16.h>
#include <hip/hip_fp16.h>

#define IN_CH 512
#define HID 16
#define OUT_CH 64

typedef __attribute__((ext_vector_type(8))) short bf16x8;
typedef __attribute__((ext_vector_type(4))) float f32x4;

__device__ inline unsigned short f2bf(float f) {   // RNE truncate to bf16
    unsigned int u = __float_as_uint(f);
    return (unsigned short)((u + 0x7fffu + ((u >> 16) & 1u)) >> 16);
}

union A8 { bf16x8 v; short2 p[4]; };
__device__ inline short2 pk2(float a, float b) {
    union { __hip_bfloat162 h; short2 s; } u;
    u.h = __float22bfloat162_rn(make_float2(a, b));
    return u.s;
}

// ---------------- zero counters ----------------
__global__ void k_zero(int* __restrict__ cnt, float* __restrict__ degf, int N) {
    int i = blockIdx.x * 256 + threadIdx.x;
    if (i < N) { cnt[i] = 0; degf[i] = 0.f; }
}

// ---------------- Phase 1: per-node count + weighted degree via global atomics ----
// Fire-and-forget atomics into 800 KB (L2-resident); 12.5K blocks of parallelism.
__global__ void k_hist(const int* __restrict__ ei1, const float* __restrict__ w1, int E1,
                       const int* __restrict__ ei2, const float* __restrict__ w2, int E2,
                       int* __restrict__ cnt, float* __restrict__ degf, int Et) {
    int e = blockIdx.x * 256 + threadIdx.x;
    if (e >= Et) return;
    int r; float w;
    if (e < E1) { r = ei1[e]; w = w1[e]; }
    else        { int f = e - E1; r = ei2[f]; w = w2[f]; }
    atomicAdd(&cnt[r], 1);
    atomicAdd(&degf[r], w);
}

// ---------------- Phase 2a: per-512-chunk exclusive scan + dinv ----------------
__global__ __launch_bounds__(512) void k_scan1(const int* __restrict__ cnt,
                                               const float* __restrict__ degf,
                                               int2* __restrict__ rowmeta,
                                               int* __restrict__ btot,
                                               float* __restrict__ dinv, int N) {
    __shared__ int s[512];
    int b = blockIdx.x, tid = threadIdx.x;
    int node = b * 512 + tid;
    int v = (node < N) ? cnt[node] : 0;
    s[tid] = v;
    __syncthreads();
    for (int off = 1; off < 512; off <<= 1) {
        int t = (tid >= off) ? s[tid - off] : 0;
        __syncthreads();
        s[tid] += t;
        __syncthreads();
    }
    if (node < N) {
        rowmeta[node] = make_int2(s[tid] - v, v);   // local exclusive; base added in k_apply
        float d = degf[node];
        dinv[node] = (d > 0.f) ? rsqrtf(fmaxf(d, 1e-12f)) : 0.f;
    }
    if (tid == 511) btot[b] = s[511];
}

// ---------------- Phase 2b: scan the 196 chunk totals ----------------
__global__ void k_scan2(const int* __restrict__ btot, int* __restrict__ cbase, int nbk) {
    __shared__ int s[256];
    int tid = threadIdx.x;
    int v = (tid < nbk) ? btot[tid] : 0;
    s[tid] = v;
    __syncthreads();
    for (int off = 1; off < 256; off <<= 1) {
        int t = (tid >= off) ? s[tid - off] : 0;
        __syncthreads();
        s[tid] += t;
        __syncthreads();
    }
    if (tid < nbk) cbase[tid] = s[tid] - v;  // exclusive
}

// ---------------- Phase 2c: apply chunk base -> absolute rowstart ----------------
// rowmeta.x becomes the scatter cursor (ends at rowstart+cnt after k_scatter;
// agg kernels recompute start = end - cnt).
__global__ void k_apply(int2* __restrict__ rowmeta, const int* __restrict__ cbase, int N) {
    int node = blockIdx.x * 256 + threadIdx.x;
    if (node >= N) return;
    int2 rm = rowmeta[node];
    rowmeta[node] = make_int2(rm.x + cbase[node >> 9], rm.y);
}

// ---------------- Phase 3: direct scatter into CSR via global cursor atomics ----
__global__ void k_scatter(const int* __restrict__ ei1, const float* __restrict__ w1, int E1,
                          const int* __restrict__ ei2, const float* __restrict__ w2, int E2,
                          int2* __restrict__ rowmeta, int2* __restrict__ csr, int Et) {
    int e = blockIdx.x * 256 + threadIdx.x;
    if (e >= Et) return;
    int r, c; float w;
    if (e < E1) { r = ei1[e]; c = ei1[e + E1]; w = w1[e]; }
    else        { int f = e - E1; r = ei2[f]; c = ei2[f + E2]; w = w2[f]; }
    int pos = atomicAdd(&((int*)rowmeta)[2 * r], 1);   // rowmeta[r].x++
    csr[pos] = make_int2(c, (int)__float_as_uint(w));
}

// ---------------- prep: W1 -> bf16, swizzled into B-fragment order ----------------
// W1s[(kc*64+lane)*8 + j] = bf16(W1[(kc*32 + (lane>>4)*8 + j)*16 + (lane&15)])
__global__ void k_prep(const float* __restrict__ W1, unsigned short* __restrict__ W1s) {
    for (int p = threadIdx.x; p < 1024; p += 256) {
        int kc = p >> 6, lane = p & 63;
        int q = lane >> 4, m = lane & 15;
        int k0 = kc * 32 + q * 8;
        unsigned v[8];
        #pragma unroll
        for (int j = 0; j < 8; ++j) v[j] = f2bf(W1[(k0 + j) * HID + m]);
        uint4 o;
        o.x = v[0] | (v[1] << 16); o.y = v[2] | (v[3] << 16);
        o.z = v[4] | (v[5] << 16); o.w = v[6] | (v[7] << 16);
        ((uint4*)W1s)[p] = o;
    }
}

// ---------------- h1s = f16(dinv * (x @ W1)) via MFMA bf16 ----------------
__global__ __launch_bounds__(256) void k_gemm1(const float* __restrict__ x,
                                               const unsigned short* __restrict__ W1s,
                                               const float* __restrict__ dinv,
                                               __half* __restrict__ h1s, int n) {
    int wave = threadIdx.x >> 6, lane = threadIdx.x & 63;
    int tiles = (n + 15) >> 4;
    int t = blockIdx.x * 4 + wave;
    if (t >= tiles) return;

    int m = lane & 15, quad = lane >> 4;

    const bf16x8* Wv = (const bf16x8*)W1s;
    bf16x8 Bf[16];
    #pragma unroll
    for (int kc = 0; kc < 16; ++kc) Bf[kc] = Wv[kc * 64 + lane];   // 16B contiguous

    int row = t * 16 + m;
    int rl = min(row, n - 1);
    const float4* xr = (const float4*)(x + (size_t)rl * IN_CH + quad * 8);

    f32x4 acc = {0.f, 0.f, 0.f, 0.f};
    #pragma unroll
    for (int kc = 0; kc < 16; ++kc) {
        float4 v0 = xr[kc * 8];
        float4 v1 = xr[kc * 8 + 1];
        A8 a;
        a.p[0] = pk2(v0.x, v0.y); a.p[1] = pk2(v0.z, v0.w);
        a.p[2] = pk2(v1.x, v1.y); a.p[3] = pk2(v1.z, v1.w);
        acc = __builtin_amdgcn_mfma_f32_16x16x32_bf16(a.v, Bf[kc], acc, 0, 0, 0);
    }

    int base = t * 16 + quad * 4;
    #pragma unroll
    for (int r = 0; r < 4; ++r) {
        int orow = base + r;
        if (orow < n) h1s[(size_t)orow * HID + m] = __float2half(dinv[orow] * acc[r]);
    }
}

// ---------------- out1s = f16(dinv * relu(dinv*aggregate(h1s) + b1)) ----------------
// lane = (slot=lane>>2 edge slot, c4=lane&3 channel quad). 16 edges in flight,
// 8B f16x4 gathers. rowmeta = (end, cnt) after scatter -> start = end - cnt.
__global__ __launch_bounds__(256) void k_agg1(const __half* __restrict__ h1s,
                                              const int2* __restrict__ csr,
                                              const int2* __restrict__ rowmeta,
                                              const float* __restrict__ dinv,
                                              const float* __restrict__ b1,
                                              __half* __restrict__ out1s, int n) {
    int wave = threadIdx.x >> 6, lane = threadIdx.x & 63;
    int node = blockIdx.x * 4 + wave;
    if (node >= n) return;
    int slot = lane >> 2, c4 = lane & 3;
    int2 rm = rowmeta[node];
    int deg = rm.y;
    const int2* ce = csr + (rm.x - deg);
    f32x4 acc = {0.f, 0.f, 0.f, 0.f};
    for (int i = slot; i < deg; i += 16) {
        int2 e = ce[i];
        float w = __int_as_float(e.y);
        uint2 raw = ((const uint2*)(h1s + (size_t)e.x * HID))[c4];
        float2 f01 = __half22float2(*(const __half2*)&raw.x);
        float2 f23 = __half22float2(*(const __half2*)&raw.y);
        acc[0] = fmaf(w, f01.x, acc[0]); acc[1] = fmaf(w, f01.y, acc[1]);
        acc[2] = fmaf(w, f23.x, acc[2]); acc[3] = fmaf(w, f23.y, acc[3]);
    }
    #pragma unroll
    for (int off = 4; off < 64; off <<= 1) {
        acc[0] += __shfl_xor(acc[0], off, 64);
        acc[1] += __shfl_xor(acc[1], off, 64);
        acc[2] += __shfl_xor(acc[2], off, 64);
        acc[3] += __shfl_xor(acc[3], off, 64);
    }
    if (lane < 4) {
        float dv = dinv[node];
        float4 bb = ((const float4*)b1)[c4];
        float4 o;
        o.x = fmaxf(fmaf(dv, acc[0], bb.x), 0.f) * dv;
        o.y = fmaxf(fmaf(dv, acc[1], bb.y), 0.f) * dv;
        o.z = fmaxf(fmaf(dv, acc[2], bb.z), 0.f) * dv;
        o.w = fmaxf(fmaf(dv, acc[3], bb.w), 0.f) * dv;
        __half2 p01 = __float22half2_rn(make_float2(o.x, o.y));
        __half2 p23 = __float22half2_rn(make_float2(o.z, o.w));
        uint2 st;
        st.x = *(unsigned*)&p01; st.y = *(unsigned*)&p23;
        ((uint2*)(out1s + (size_t)node * HID))[c4] = st;
    }
}

// ---------------- layer2: agg(out1s) -> 16->64 GEMM -> log_softmax ----------------
__global__ __launch_bounds__(256) void k_layer2(const __half* __restrict__ out1s,
                                                const int2* __restrict__ csr,
                                                const int2* __restrict__ rowmeta,
                                                const float* __restrict__ dinv,
                                                const float* __restrict__ W2,
                                                const float* __restrict__ b2,
                                                float* __restrict__ out, int n) {
    __shared__ float W2l[HID * OUT_CH];
    for (int i = threadIdx.x; i < HID * OUT_CH; i += 256) W2l[i] = W2[i];
    __syncthreads();

    int wave = threadIdx.x >> 6, lane = threadIdx.x & 63;
    int node = blockIdx.x * 4 + wave;
    if (node >= n) return;
    int slot = lane >> 2, c4 = lane & 3;
    int2 rm = rowmeta[node];
    int deg = rm.y;
    const int2* ce = csr + (rm.x - deg);
    f32x4 acc = {0.f, 0.f, 0.f, 0.f};
    for (int i = slot; i < deg; i += 16) {
        int2 e = ce[i];
        float w = __int_as_float(e.y);
        uint2 raw = ((const uint2*)(out1s + (size_t)e.x * HID))[c4];
        float2 f01 = __half22float2(*(const __half2*)&raw.x);
        float2 f23 = __half22float2(*(const __half2*)&raw.y);
        acc[0] = fmaf(w, f01.x, acc[0]); acc[1] = fmaf(w, f01.y, acc[1]);
        acc[2] = fmaf(w, f23.x, acc[2]); acc[3] = fmaf(w, f23.y, acc[3]);
    }
    #pragma unroll
    for (int off = 4; off < 64; off <<= 1) {
        acc[0] += __shfl_xor(acc[0], off, 64);
        acc[1] += __shfl_xor(acc[1], off, 64);
        acc[2] += __shfl_xor(acc[2], off, 64);
        acc[3] += __shfl_xor(acc[3], off, 64);
    }
    float dv = dinv[node];
    acc[0] *= dv; acc[1] *= dv; acc[2] *= dv; acc[3] *= dv;
    // lane j needs all 16 agg values: lane gg (gg<4) holds channels 4gg..4gg+3
    float v = b2[lane];
    #pragma unroll
    for (int gg = 0; gg < 4; ++gg) {
        float a0 = __shfl(acc[0], gg, 64);
        float a1 = __shfl(acc[1], gg, 64);
        float a2 = __shfl(acc[2], gg, 64);
        float a3 = __shfl(acc[3], gg, 64);
        v = fmaf(a0, W2l[(4 * gg + 0) * OUT_CH + lane], v);
        v = fmaf(a1, W2l[(4 * gg + 1) * OUT_CH + lane], v);
        v = fmaf(a2, W2l[(4 * gg + 2) * OUT_CH + lane], v);
        v = fmaf(a3, W2l[(4 * gg + 3) * OUT_CH + lane], v);
    }
    float m = v;
    #pragma unroll
    for (int off = 32; off; off >>= 1) m = fmaxf(m, __shfl_xor(m, off, 64));
    float ex = __expf(v - m);
    float s = ex;
    #pragma unroll
    for (int off = 32; off; off >>= 1) s += __shfl_xor(s, off, 64);
    out[(size_t)node * OUT_CH + lane] = (v - m) - __logf(s);
}

extern "C" void kernel_launch(void* const* d_in, const int* in_sizes, int n_in,
                              void* d_out, int out_size, void* d_ws, size_t ws_size,
                              hipStream_t stream) {
    const float* x   = (const float*)d_in[0];
    const int*   ei1 = (const int*)d_in[1];
    const float* w1  = (const float*)d_in[2];
    const int*   ei2 = (const int*)d_in[3];
    const float* w2  = (const float*)d_in[4];
    const float* W1  = (const float*)d_in[5];
    const float* b1  = (const float*)d_in[6];
    const float* W2  = (const float*)d_in[7];
    const float* b2  = (const float*)d_in[8];
    int N  = in_sizes[0] / IN_CH;
    int E1 = in_sizes[2];
    int E2 = in_sizes[4];
    int Et = E1 + E2;
    float* out = (float*)d_out;
    int nbk = (N + 511) >> 9;   // 196 chunks of 512 nodes

    // workspace layout (no packed buffer anymore -> ~35 MB total)
    char* p = (char*)d_ws;
    int*   cnt      = (int*)p;   p += (size_t)N * 4;
    float* degf     = (float*)p; p += (size_t)N * 4;
    int*   btot     = (int*)p;   p += 1024;
    int*   cbase    = (int*)p;   p += 1024;
    int2*  rowmeta  = (int2*)p;  p += (size_t)N * 8;
    float* dinv     = (float*)p; p += (size_t)N * 4;
    unsigned short* W1s = (unsigned short*)p; p += IN_CH * HID * 2;
    int2*  csr      = (int2*)p;  p += (size_t)Et * 8;   // 25.6 MB
    __half* h1s     = (__half*)p; p += (size_t)N * HID * 2;  // 3.2 MB
    __half* out1s   = (__half*)p;                            // 3.2 MB

    int egrid = (Et + 255) / 256;
    int ngrid = (N + 255) / 256;

    k_zero<<<ngrid, 256, 0, stream>>>(cnt, degf, N);
    k_prep<<<1, 256, 0, stream>>>(W1, W1s);
    k_hist<<<egrid, 256, 0, stream>>>(ei1, w1, E1, ei2, w2, E2, cnt, degf, Et);
    k_scan1<<<nbk, 512, 0, stream>>>(cnt, degf, rowmeta, btot, dinv, N);
    k_scan2<<<1, 256, 0, stream>>>(btot, cbase, nbk);
    k_apply<<<ngrid, 256, 0, stream>>>(rowmeta, cbase, N);
    k_scatter<<<egrid, 256, 0, stream>>>(ei1, w1, E1, ei2, w2, E2, rowmeta, csr, Et);
    int tiles = (N + 15) / 16;
    k_gemm1<<<(tiles + 3) / 4, 256, 0, stream>>>(x, W1s, dinv, h1s, N);
    k_agg1<<<(N + 3) / 4, 256, 0, stream>>>(h1s, csr, rowmeta, dinv, b1, out1s, N);
    k_layer2<<<(N + 3) / 4, 256, 0, stream>>>(out1s, csr, rowmeta, dinv, W2, b2, out, N);
}